// Round 1
// baseline (33.567 us; speedup 1.0000x reference)
//
#include <hip/hip_runtime.h>

// 2D Haar analysis: x (32,3,512,512) f32 -> out (32,3,4,256,256) f32
// out[..,0]=cA, 1=cH, 2=cV, 3=cD
// Each thread: load float4 from row 2i (cols 4j..4j+3) + float4 from row 2i+1,
// produce 2 output columns (float2) in each of the 4 coefficient planes.

__global__ __launch_bounds__(256) void
WaveletTransform_53309134078401_kernel(const float* __restrict__ x,
                                       float* __restrict__ out) {
    const int tid = blockIdx.x * blockDim.x + threadIdx.x;
    // decompose: 128 float4-columns, 256 output rows, 96 (b,c) planes
    const int j4 = tid & 127;          // which float4 (covers input cols 4*j4..4*j4+3)
    const int i  = (tid >> 7) & 255;   // output row
    const int bc = tid >> 15;          // plane index 0..95

    const float* row0 = x + (size_t)bc * (512 * 512) + (size_t)(2 * i) * 512 + j4 * 4;
    const float4 v0 = *reinterpret_cast<const float4*>(row0);
    const float4 v1 = *reinterpret_cast<const float4*>(row0 + 512);

    float2 cA, cH, cV, cD;
    {   // output column 2*j4 : x00=v0.x x01=v0.y x10=v1.x x11=v1.y
        const float s0 = v0.x + v0.y, d0 = v0.x - v0.y;
        const float s1 = v1.x + v1.y, d1 = v1.x - v1.y;
        cA.x = (s0 + s1) * 0.5f;
        cH.x = (s0 - s1) * 0.5f;
        cV.x = (d0 + d1) * 0.5f;
        cD.x = (d0 - d1) * 0.5f;
    }
    {   // output column 2*j4+1
        const float s0 = v0.z + v0.w, d0 = v0.z - v0.w;
        const float s1 = v1.z + v1.w, d1 = v1.z - v1.w;
        cA.y = (s0 + s1) * 0.5f;
        cH.y = (s0 - s1) * 0.5f;
        cV.y = (d0 + d1) * 0.5f;
        cD.y = (d0 - d1) * 0.5f;
    }

    float* ob = out + (size_t)bc * (4 * 256 * 256) + (size_t)i * 256 + j4 * 2;
    *reinterpret_cast<float2*>(ob + 0 * 65536) = cA;
    *reinterpret_cast<float2*>(ob + 1 * 65536) = cH;
    *reinterpret_cast<float2*>(ob + 2 * 65536) = cV;
    *reinterpret_cast<float2*>(ob + 3 * 65536) = cD;
}

extern "C" void kernel_launch(void* const* d_in, const int* in_sizes, int n_in,
                              void* d_out, int out_size, void* d_ws, size_t ws_size,
                              hipStream_t stream) {
    const float* x = (const float*)d_in[0];
    float* out = (float*)d_out;
    // total threads: 96 planes * 256 rows * 128 float4-cols = 3,145,728
    const int total = 96 * 256 * 128;
    const int block = 256;
    const int grid = total / block;  // 12288
    WaveletTransform_53309134078401_kernel<<<grid, block, 0, stream>>>(x, out);
}